// Round 18
// baseline (150.614 us; speedup 1.0000x reference)
//
#include <hip/hip_runtime.h>

#define N_NODES 50000
#define PADROWS 50176   // 196*256, branchless A loads (256-row tiles)
#define N_EDGES 600000
#define NPART 196   // ceil(50000/256)
#define MAXDEG 64   // Poisson(12): P(deg>64) ~ e^-57; clamp-guarded anyway

using f32x4  = __attribute__((ext_vector_type(4))) float;
using bf16x8 = __attribute__((ext_vector_type(8))) short;

__device__ inline ushort f2bf(float f) {
    uint32_t u = __builtin_bit_cast(uint32_t, f);
    uint32_t r = (u + 0x7FFFu + ((u >> 16) & 1u)) >> 16;
    return (ushort)r;
}
__device__ inline float bf2f(ushort h) {
    uint32_t u = ((uint32_t)h) << 16;
    return __builtin_bit_cast(float, u);
}

// ---------------------------------------------------------------- adjacency build (CSR-free)
// Padded [node][MAXDEG] USHORT lists (node ids < 2^16): halves the scattered-
// write line working set (12.8->6.4MB; 2 lines/node) -> less per-XCD L2 churn.

__global__ void fill_kernel(const int* __restrict__ src, const int* __restrict__ dst,
                            int* __restrict__ cursor, ushort* __restrict__ col) {
    int e = blockIdx.x * blockDim.x + threadIdx.x;
    if (e < N_EDGES) {
        int d = dst[e];
        int pos = atomicAdd(&cursor[d], 1);
        if (pos < MAXDEG) col[(size_t)d * MAXDEG + pos] = (ushort)src[e];
    }
}

// ---------------------------------------------------------------- prep (one launch):
// zero(cursor) + W0/W1 transpose (bf16 hi) + W2cat hi/lo + x cast

__device__ inline void wsplit_hi(const float* __restrict__ Ws, const float* __restrict__ Wn,
                                 short* __restrict__ Wh, int nout, int idx) {
    int c = idx >> 8, k = idx & 255;
    float v = (k < 128) ? Ws[(size_t)k * nout + c] : Wn[(size_t)(k - 128) * nout + c];
    Wh[idx] = (short)f2bf(v);
}

__global__ void prep_kernel(const float* __restrict__ Ws0, const float* __restrict__ Wn0,
                            const float* __restrict__ Ws1, const float* __restrict__ Wn1,
                            const float* __restrict__ Ws2, const float* __restrict__ Wn2,
                            const float* __restrict__ x,
                            int* __restrict__ cursor,
                            short* __restrict__ W0h,
                            short* __restrict__ W1h,
                            short* __restrict__ W2h, short* __restrict__ W2l,
                            ushort* __restrict__ nbh) {
    int b = blockIdx.x, t = threadIdx.x;
    if (b < 196) {
        int i = b * 256 + t;
        if (i < N_NODES) cursor[i] = 0;
    } else if (b < 324) {
        wsplit_hi(Ws0, Wn0, W0h, 128, (b - 196) * 256 + t);
    } else if (b < 452) {
        wsplit_hi(Ws1, Wn1, W1h, 128, (b - 324) * 256 + t);
    } else if (b < 516) {
        // W2cat[c][k] hi/lo, c<64 -> Ws2 col c, else Wn2 col c-64; K=128
        int idx = (b - 452) * 256 + t;       // < 16384
        int c = idx >> 7, kk = idx & 127;
        float v = (c < 64) ? Ws2[(size_t)kk * 64 + c] : Wn2[(size_t)kk * 64 + (c - 64)];
        ushort hi = f2bf(v);
        W2h[idx] = (short)hi;
        W2l[idx] = (short)f2bf(v - bf2f(hi));
    } else {
        int i = (b - 516) * 256 + t;          // 4 floats per thread
        if (i < N_NODES * 32) {
            f32x4 v = *(const f32x4*)(x + (size_t)i * 4);
            ushort4 h4;
            h4.x = f2bf(v[0]); h4.y = f2bf(v[1]);
            h4.z = f2bf(v[2]); h4.w = f2bf(v[3]);
            *(ushort4*)(nbh + (size_t)i * 4) = h4;
        }
    }
}

// ---------------------------------------------------------------- aggregate (layers 0/1)
// Wave = 4 nodes x 16 lanes; lane owns 8 cols (uint4) end-to-end; edge indices
// (ushort) batch-loaded then shfl-broadcast; unroll-8 for MLP.

__global__ __launch_bounds__(256) void aggregate_kernel(
    const ushort* __restrict__ hb, const int* __restrict__ cursor,
    const ushort* __restrict__ col, uint32_t* __restrict__ aggh)
{
    int node = blockIdx.x * 16 + (threadIdx.x >> 4);
    int cl = threadIdx.x & 15;            // uint4 chunk: cols 8cl..8cl+7
    if (node >= N_NODES) return;

    int beg = node * MAXDEG;
    int deg = min(cursor[node], MAXDEG);

    const ushort* gcol = hb + cl * 8;
    float s0 = 0.f, s1 = 0.f, s2 = 0.f, s3 = 0.f;
    float s4 = 0.f, s5 = 0.f, s6 = 0.f, s7 = 0.f;

#define ACCUM(U) do {                                                        \
        s0 += __builtin_bit_cast(float, (U).x << 16);                        \
        s1 += __builtin_bit_cast(float, (U).x & 0xffff0000u);                \
        s2 += __builtin_bit_cast(float, (U).y << 16);                        \
        s3 += __builtin_bit_cast(float, (U).y & 0xffff0000u);                \
        s4 += __builtin_bit_cast(float, (U).z << 16);                        \
        s5 += __builtin_bit_cast(float, (U).z & 0xffff0000u);                \
        s6 += __builtin_bit_cast(float, (U).w << 16);                        \
        s7 += __builtin_bit_cast(float, (U).w & 0xffff0000u);                \
    } while (0)

    for (int j = 0; j < deg; j += 16) {
        int nb = min(16, deg - j);
        int myidx = (j + cl < deg) ? (int)col[beg + j + cl] : 0;
        int t = 0;
        for (; t + 7 < nb; t += 8) {
            int i0 = __shfl(myidx, t, 16);
            int i1 = __shfl(myidx, t + 1, 16);
            int i2 = __shfl(myidx, t + 2, 16);
            int i3 = __shfl(myidx, t + 3, 16);
            int i4 = __shfl(myidx, t + 4, 16);
            int i5 = __shfl(myidx, t + 5, 16);
            int i6 = __shfl(myidx, t + 6, 16);
            int i7 = __shfl(myidx, t + 7, 16);
            uint4 u0 = *(const uint4*)(gcol + (size_t)i0 * 128);
            uint4 u1 = *(const uint4*)(gcol + (size_t)i1 * 128);
            uint4 u2 = *(const uint4*)(gcol + (size_t)i2 * 128);
            uint4 u3 = *(const uint4*)(gcol + (size_t)i3 * 128);
            uint4 u4 = *(const uint4*)(gcol + (size_t)i4 * 128);
            uint4 u5 = *(const uint4*)(gcol + (size_t)i5 * 128);
            uint4 u6 = *(const uint4*)(gcol + (size_t)i6 * 128);
            uint4 u7 = *(const uint4*)(gcol + (size_t)i7 * 128);
            ACCUM(u0); ACCUM(u1); ACCUM(u2); ACCUM(u3);
            ACCUM(u4); ACCUM(u5); ACCUM(u6); ACCUM(u7);
        }
        for (; t + 3 < nb; t += 4) {
            int i0 = __shfl(myidx, t, 16);
            int i1 = __shfl(myidx, t + 1, 16);
            int i2 = __shfl(myidx, t + 2, 16);
            int i3 = __shfl(myidx, t + 3, 16);
            uint4 u0 = *(const uint4*)(gcol + (size_t)i0 * 128);
            uint4 u1 = *(const uint4*)(gcol + (size_t)i1 * 128);
            uint4 u2 = *(const uint4*)(gcol + (size_t)i2 * 128);
            uint4 u3 = *(const uint4*)(gcol + (size_t)i3 * 128);
            ACCUM(u0); ACCUM(u1); ACCUM(u2); ACCUM(u3);
        }
        for (; t < nb; ++t) {
            int i0 = __shfl(myidx, t, 16);
            uint4 u0 = *(const uint4*)(gcol + (size_t)i0 * 128);
            ACCUM(u0);
        }
    }
#undef ACCUM

    float dinv = 1.0f / (float)max(deg, 1);
    ushort h0 = f2bf(s0 * dinv), h1 = f2bf(s1 * dinv);
    ushort h2 = f2bf(s2 * dinv), h3 = f2bf(s3 * dinv);
    ushort h4 = f2bf(s4 * dinv), h5 = f2bf(s5 * dinv);
    ushort h6 = f2bf(s6 * dinv), h7 = f2bf(s7 * dinv);
    uint4 w;
    w.x = (uint32_t)h0 | ((uint32_t)h1 << 16);
    w.y = (uint32_t)h2 | ((uint32_t)h3 << 16);
    w.z = (uint32_t)h4 | ((uint32_t)h5 << 16);
    w.w = (uint32_t)h6 | ((uint32_t)h7 << 16);
    ((uint4*)aggh)[(size_t)node * 16 + cl] = w;
}

// ---------------------------------------------------------------- aggregate_out (layer 2, transform-first)
// T = [u|v] bf16 per row (128 cols). Gathers v (128B rows), fuses
// out = u + mean(v[src]). Wave = 8 nodes x 8 lanes.

__global__ __launch_bounds__(256) void aggregate_out_kernel(
    const ushort* __restrict__ T, const int* __restrict__ cursor,
    const ushort* __restrict__ col, float* __restrict__ out)
{
    int node = blockIdx.x * 32 + (threadIdx.x >> 3);
    int cl = threadIdx.x & 7;             // uint4 chunk: cols 8cl..8cl+7 of v
    if (node >= N_NODES) return;

    int beg = node * MAXDEG;
    int deg = min(cursor[node], MAXDEG);

    const ushort* gcol = T + 64 + cl * 8;  // v = cols 64..127
    float s0 = 0.f, s1 = 0.f, s2 = 0.f, s3 = 0.f;
    float s4 = 0.f, s5 = 0.f, s6 = 0.f, s7 = 0.f;

#define ACCUM(U) do {                                                        \
        s0 += __builtin_bit_cast(float, (U).x << 16);                        \
        s1 += __builtin_bit_cast(float, (U).x & 0xffff0000u);                \
        s2 += __builtin_bit_cast(float, (U).y << 16);                        \
        s3 += __builtin_bit_cast(float, (U).y & 0xffff0000u);                \
        s4 += __builtin_bit_cast(float, (U).z << 16);                        \
        s5 += __builtin_bit_cast(float, (U).z & 0xffff0000u);                \
        s6 += __builtin_bit_cast(float, (U).w << 16);                        \
        s7 += __builtin_bit_cast(float, (U).w & 0xffff0000u);                \
    } while (0)

    for (int j = 0; j < deg; j += 8) {
        int nb = min(8, deg - j);
        int myidx = (j + cl < deg) ? (int)col[beg + j + cl] : 0;
        int t = 0;
        for (; t + 3 < nb; t += 4) {
            int i0 = __shfl(myidx, t, 8);
            int i1 = __shfl(myidx, t + 1, 8);
            int i2 = __shfl(myidx, t + 2, 8);
            int i3 = __shfl(myidx, t + 3, 8);
            uint4 u0 = *(const uint4*)(gcol + (size_t)i0 * 128);
            uint4 u1 = *(const uint4*)(gcol + (size_t)i1 * 128);
            uint4 u2 = *(const uint4*)(gcol + (size_t)i2 * 128);
            uint4 u3 = *(const uint4*)(gcol + (size_t)i3 * 128);
            ACCUM(u0); ACCUM(u1); ACCUM(u2); ACCUM(u3);
        }
        for (; t < nb; ++t) {
            int i0 = __shfl(myidx, t, 8);
            uint4 u0 = *(const uint4*)(gcol + (size_t)i0 * 128);
            ACCUM(u0);
        }
    }
#undef ACCUM

    float dinv = 1.0f / (float)max(deg, 1);
    uint4 uu = *(const uint4*)(T + (size_t)node * 128 + cl * 8);
    float4 o0, o1;
    o0.x = __builtin_bit_cast(float, uu.x << 16)          + s0 * dinv;
    o0.y = __builtin_bit_cast(float, uu.x & 0xffff0000u)  + s1 * dinv;
    o0.z = __builtin_bit_cast(float, uu.y << 16)          + s2 * dinv;
    o0.w = __builtin_bit_cast(float, uu.y & 0xffff0000u)  + s3 * dinv;
    o1.x = __builtin_bit_cast(float, uu.z << 16)          + s4 * dinv;
    o1.y = __builtin_bit_cast(float, uu.z & 0xffff0000u)  + s5 * dinv;
    o1.z = __builtin_bit_cast(float, uu.w << 16)          + s6 * dinv;
    o1.w = __builtin_bit_cast(float, uu.w & 0xffff0000u)  + s7 * dinv;
    *(float4*)(out + (size_t)node * 64 + cl * 8)     = o0;
    *(float4*)(out + (size_t)node * 64 + cl * 8 + 4) = o1;
}

// ---------------------------------------------------------------- combine GEMM v13 (layers 0/1, plain bf16 both sides)

template <int NOUT, int CB, bool RELU>
__global__ __launch_bounds__(512) void combine_mfma13(
    const ushort* __restrict__ nbh, const ushort* __restrict__ aggh,
    const short* __restrict__ Wth,
    const float* __restrict__ bias, ushort* __restrict__ oh)
{
    __shared__ __attribute__((aligned(16))) short Bh[64 * 33 * 8];

    const int id  = blockIdx.x;          // grid = 8 * 25 * CB
    const int xcd = id & 7;
    const int k   = id >> 3;
    const int rb  = k / CB;
    const int cnt_x = (xcd < 4) ? 25 : 24;
    if (rb >= cnt_x) return;
    const int base  = (xcd < 4) ? xcd * 25 : 100 + (xcd - 4) * 24;
    const int row0    = (base + rb) * 256;
    const int colbase = (k % CB) * 64;

    const int tid  = threadIdx.x;
    const int lane = tid & 63;
    const int wave = tid >> 6;
    const int rr = lane & 15;
    const int kq = lane >> 4;

    // stage B once: 64 cols x 32 chunks (2048 chunks / 512 thr = 4 each)
    {
        int col = tid >> 3;
        int kc0 = (tid & 7) * 4;
        const short* gh = Wth + (size_t)(colbase + col) * 256 + kc0 * 8;
        #pragma unroll
        for (int j = 0; j < 4; ++j)
            ((bf16x8*)Bh)[col * 33 + kc0 + j] = *(const bf16x8*)(gh + j * 8);
    }

    const size_t arow0 = (size_t)(row0 + wave * 32 + rr) * 128;
    const size_t arow1 = arow0 + (size_t)16 * 128;

    f32x4 acc[2][4];
    #pragma unroll
    for (int i = 0; i < 2; ++i)
        #pragma unroll
        for (int j = 0; j < 4; ++j)
            acc[i][j] = (f32x4){0.f, 0.f, 0.f, 0.f};

    __syncthreads();

#define COMPUTE(KS) do {                                                    \
        const ushort* bs_ = ((KS) < 4) ? nbh : aggh;                        \
        const int kf_ = ((KS) & 3) * 32 + kq * 8;                           \
        bf16x8 aA = *(const bf16x8*)(bs_ + arow0 + kf_);                    \
        bf16x8 aB = *(const bf16x8*)(bs_ + arow1 + kf_);                    \
        _Pragma("unroll")                                                   \
        for (int nj = 0; nj < 4; ++nj) {                                    \
            int colL = nj * 16 + rr;                                        \
            bf16x8 bh = ((const bf16x8*)Bh)[colL * 33 + (KS) * 4 + kq];     \
            acc[0][nj] = __builtin_amdgcn_mfma_f32_16x16x32_bf16(aA, bh, acc[0][nj], 0, 0, 0); \
            acc[1][nj] = __builtin_amdgcn_mfma_f32_16x16x32_bf16(aB, bh, acc[1][nj], 0, 0, 0); \
        }                                                                   \
    } while (0)

    COMPUTE(0); COMPUTE(1); COMPUTE(2); COMPUTE(3);
    COMPUTE(4); COMPUTE(5); COMPUTE(6); COMPUTE(7);
#undef COMPUTE

    const int rg = lane >> 4;
    #pragma unroll
    for (int nj = 0; nj < 4; ++nj) {
        int colg = colbase + nj * 16 + rr;
        float bv = bias[colg];
        #pragma unroll
        for (int mi = 0; mi < 2; ++mi) {
            #pragma unroll
            for (int r = 0; r < 4; ++r) {
                int row = row0 + wave * 32 + mi * 16 + rg * 4 + r;
                if (row < N_NODES) {
                    float v = acc[mi][nj][r] + bv;
                    if (RELU) v = fmaxf(v, 0.f);
                    oh[(size_t)row * NOUT + colg] = f2bf(v);
                }
            }
        }
    }
}

// ---------------------------------------------------------------- combine GEMM v12 (layer 2, transform-first, B hi/lo)
// T[n] = hB[n] @ [Ws2|Wn2] (+ [b2|0]), K=128, NOUT=128, bf16 out.

__global__ __launch_bounds__(512, 4) void combine_mfma12(
    const ushort* __restrict__ hb,
    const short* __restrict__ Wth, const short* __restrict__ Wtl,
    const float* __restrict__ b2, ushort* __restrict__ T)
{
    __shared__ __attribute__((aligned(16))) short Bh[128 * 17 * 8];
    __shared__ __attribute__((aligned(16))) short Bl[128 * 17 * 8];

    const int id  = blockIdx.x;          // grid = 200
    const int xcd = id & 7;
    const int k   = id >> 3;
    const int cnt_x = (xcd < 4) ? 25 : 24;
    if (k >= cnt_x) return;
    const int base = (xcd < 4) ? xcd * 25 : 100 + (xcd - 4) * 24;
    const int row0 = (base + k) * 256;

    const int tid  = threadIdx.x;
    const int lane = tid & 63;
    const int wave = tid >> 6;
    const int rr = lane & 15;
    const int kq = lane >> 4;

    {
        int col = tid >> 2;              // 0..127
        int kc0 = (tid & 3) * 4;
        const short* gh = Wth + (size_t)col * 128 + kc0 * 8;
        const short* gl = Wtl + (size_t)col * 128 + kc0 * 8;
        #pragma unroll
        for (int j = 0; j < 4; ++j) {
            ((bf16x8*)Bh)[col * 17 + kc0 + j] = *(const bf16x8*)(gh + j * 8);
            ((bf16x8*)Bl)[col * 17 + kc0 + j] = *(const bf16x8*)(gl + j * 8);
        }
    }

    const size_t arow0 = (size_t)(row0 + wave * 32 + rr) * 128;
    const size_t arow1 = arow0 + (size_t)16 * 128;

    f32x4 acc[2][8];
    #pragma unroll
    for (int i = 0; i < 2; ++i)
        #pragma unroll
        for (int j = 0; j < 8; ++j)
            acc[i][j] = (f32x4){0.f, 0.f, 0.f, 0.f};

    __syncthreads();

#define COMPUTE(KS) do {                                                    \
        const int kf_ = (KS) * 32 + kq * 8;                                 \
        bf16x8 aA = *(const bf16x8*)(hb + arow0 + kf_);                     \
        bf16x8 aB = *(const bf16x8*)(hb + arow1 + kf_);                     \
        _Pragma("unroll")                                                   \
        for (int nj = 0; nj < 8; ++nj) {                                    \
            int colL = nj * 16 + rr;                                        \
            bf16x8 bh = ((const bf16x8*)Bh)[colL * 17 + (KS) * 4 + kq];     \
            bf16x8 bl = ((const bf16x8*)Bl)[colL * 17 + (KS) * 4 + kq];     \
            acc[0][nj] = __builtin_amdgcn_mfma_f32_16x16x32_bf16(aA, bh, acc[0][nj], 0, 0, 0); \
            acc[0][nj] = __builtin_amdgcn_mfma_f32_16x16x32_bf16(aA, bl, acc[0][nj], 0, 0, 0); \
            acc[1][nj] = __builtin_amdgcn_mfma_f32_16x16x32_bf16(aB, bh, acc[1][nj], 0, 0, 0); \
            acc[1][nj] = __builtin_amdgcn_mfma_f32_16x16x32_bf16(aB, bl, acc[1][nj], 0, 0, 0); \
        }                                                                   \
    } while (0)

    COMPUTE(0); COMPUTE(1); COMPUTE(2); COMPUTE(3);
#undef COMPUTE

    const int rg = lane >> 4;
    #pragma unroll
    for (int nj = 0; nj < 8; ++nj) {
        int colg = nj * 16 + rr;
        float bv = (colg < 64) ? b2[colg] : 0.f;
        #pragma unroll
        for (int mi = 0; mi < 2; ++mi) {
            #pragma unroll
            for (int r = 0; r < 4; ++r) {
                int row = row0 + wave * 32 + mi * 16 + rg * 4 + r;
                T[(size_t)row * 128 + colg] = f2bf(acc[mi][nj][r] + bv);
            }
        }
    }
}

// ---------------------------------------------------------------- launch

extern "C" void kernel_launch(void* const* d_in, const int* in_sizes, int n_in,
                              void* d_out, int out_size, void* d_ws, size_t ws_size,
                              hipStream_t stream) {
    const float* x   = (const float*)d_in[0];
    const int*   src = (const int*)d_in[1];
    const int*   dst = (const int*)d_in[2];
    const float* Ws0 = (const float*)d_in[3];
    const float* Wn0 = (const float*)d_in[4];
    const float* b0  = (const float*)d_in[5];
    const float* Ws1 = (const float*)d_in[6];
    const float* Wn1 = (const float*)d_in[7];
    const float* b1  = (const float*)d_in[8];
    const float* Ws2 = (const float*)d_in[9];
    const float* Wn2 = (const float*)d_in[10];
    const float* b2  = (const float*)d_in[11];
    float* out = (float*)d_out;

    char* p = (char*)d_ws;
    auto alloc = [&](size_t bytes) {
        char* r = p;
        p += (bytes + 255) & ~(size_t)255;
        return r;
    };
    int*      cursor   = (int*)alloc((size_t)N_NODES * 4);
    ushort*   col      = (ushort*)alloc((size_t)N_NODES * MAXDEG * 2);
    uint32_t* aggh     = (uint32_t*)alloc((size_t)PADROWS * 64 * 4);
    ushort*   nbh0     = (ushort*)alloc((size_t)PADROWS * 128 * 2);
    ushort*   nbh1     = (ushort*)alloc((size_t)PADROWS * 128 * 2);
    ushort*   Tbuf     = (ushort*)alloc((size_t)PADROWS * 128 * 2);
    short*    Wt0_hi   = (short*)alloc((size_t)128 * 256 * 2);
    short*    Wt1_hi   = (short*)alloc((size_t)128 * 256 * 2);
    short*    Wt2_hi   = (short*)alloc((size_t)128 * 128 * 2);
    short*    Wt2_lo   = (short*)alloc((size_t)128 * 128 * 2);

    // prep: zero(cursor) + W0/W1 hi + W2 hi/lo + x cast — one launch
    prep_kernel<<<516 + (N_NODES * 32 + 255) / 256, 256, 0, stream>>>(
        Ws0, Wn0, Ws1, Wn1, Ws2, Wn2, x, cursor,
        Wt0_hi, Wt1_hi, Wt2_hi, Wt2_lo, nbh0);

    // adjacency build (padded ushort lists)
    fill_kernel<<<(N_EDGES + 255) / 256, 256, 0, stream>>>(src, dst, cursor, col);

    const int AGB = (N_NODES + 15) / 16;      // 3125

    // layer 0
    aggregate_kernel<<<AGB, 256, 0, stream>>>(nbh0, cursor, col, aggh);
    combine_mfma13<128, 2, true><<<8 * 25 * 2, 512, 0, stream>>>(
        nbh0, (const ushort*)aggh, Wt0_hi, b0, nbh1);
    // layer 1
    aggregate_kernel<<<AGB, 256, 0, stream>>>(nbh1, cursor, col, aggh);
    combine_mfma13<128, 2, true><<<8 * 25 * 2, 512, 0, stream>>>(
        nbh1, (const ushort*)aggh, Wt1_hi, b1, nbh0);
    // layer 2: transform-first — T = hB@[Ws2|Wn2]+[b2|0], then gather v + add u
    combine_mfma12<<<8 * 25, 512, 0, stream>>>(nbh0, Wt2_hi, Wt2_lo, b2, Tbuf);
    aggregate_out_kernel<<<(N_NODES + 31) / 32, 256, 0, stream>>>(Tbuf, cursor, col, out);
}

// Round 19
// 147.097 us; speedup vs baseline: 1.0239x; 1.0239x over previous
//
#include <hip/hip_runtime.h>

#define N_NODES 50000
#define PADROWS 50176   // 196*256, branchless A loads (256-row tiles)
#define N_EDGES 600000
#define NPART 196   // ceil(50000/256)
#define MAXDEG 64   // Poisson(12): P(deg>64) ~ e^-57; clamp-guarded anyway
#define PSIZE 6250  // dst-partition size = 50000/8

using f32x4  = __attribute__((ext_vector_type(4))) float;
using bf16x8 = __attribute__((ext_vector_type(8))) short;

__device__ inline ushort f2bf(float f) {
    uint32_t u = __builtin_bit_cast(uint32_t, f);
    uint32_t r = (u + 0x7FFFu + ((u >> 16) & 1u)) >> 16;
    return (ushort)r;
}
__device__ inline float bf2f(ushort h) {
    uint32_t u = ((uint32_t)h) << 16;
    return __builtin_bit_cast(float, u);
}

// ---------------------------------------------------------------- adjacency build (CSR-free, XCD-partitioned)
// blockIdx&7 = dst-partition p; round-robin dispatch puts all blocks of a
// partition on one XCD -> cursor/col atomics+stores become LOCAL-L2
// transactions (r18 showed fill is random-transaction-latency-bound, 7/8
// cross-fabric). Each partition's blocks grid-stride over ALL edges and
// filter by dst range; edges re-read 8x but dst[] is L3-resident.

#define FILLG 120   // groups per partition; grid = 8*FILLG blocks

__global__ __launch_bounds__(256) void fill_kernel(
    const int* __restrict__ src, const int* __restrict__ dst,
    int* __restrict__ cursor, ushort* __restrict__ col)
{
    const int p  = blockIdx.x & 7;
    const int g  = blockIdx.x >> 3;
    const int lo = p * PSIZE;
    const int hi = lo + PSIZE;         // 8*6250 = 50000 exactly

    for (int e = g * 256 + threadIdx.x; e < N_EDGES; e += FILLG * 256) {
        int d = dst[e];
        if (d >= lo && d < hi) {
            int pos = atomicAdd(&cursor[d], 1);
            if (pos < MAXDEG) col[(size_t)d * MAXDEG + pos] = (ushort)src[e];
        }
    }
}

// ---------------------------------------------------------------- prep (one launch):
// zero(cursor) + W0/W1 transpose (bf16 hi) + W2cat hi/lo + x cast

__device__ inline void wsplit_hi(const float* __restrict__ Ws, const float* __restrict__ Wn,
                                 short* __restrict__ Wh, int nout, int idx) {
    int c = idx >> 8, k = idx & 255;
    float v = (k < 128) ? Ws[(size_t)k * nout + c] : Wn[(size_t)(k - 128) * nout + c];
    Wh[idx] = (short)f2bf(v);
}

__global__ void prep_kernel(const float* __restrict__ Ws0, const float* __restrict__ Wn0,
                            const float* __restrict__ Ws1, const float* __restrict__ Wn1,
                            const float* __restrict__ Ws2, const float* __restrict__ Wn2,
                            const float* __restrict__ x,
                            int* __restrict__ cursor,
                            short* __restrict__ W0h,
                            short* __restrict__ W1h,
                            short* __restrict__ W2h, short* __restrict__ W2l,
                            ushort* __restrict__ nbh) {
    int b = blockIdx.x, t = threadIdx.x;
    if (b < 196) {
        int i = b * 256 + t;
        if (i < N_NODES) cursor[i] = 0;
    } else if (b < 324) {
        wsplit_hi(Ws0, Wn0, W0h, 128, (b - 196) * 256 + t);
    } else if (b < 452) {
        wsplit_hi(Ws1, Wn1, W1h, 128, (b - 324) * 256 + t);
    } else if (b < 516) {
        // W2cat[c][k] hi/lo, c<64 -> Ws2 col c, else Wn2 col c-64; K=128
        int idx = (b - 452) * 256 + t;       // < 16384
        int c = idx >> 7, kk = idx & 127;
        float v = (c < 64) ? Ws2[(size_t)kk * 64 + c] : Wn2[(size_t)kk * 64 + (c - 64)];
        ushort hi = f2bf(v);
        W2h[idx] = (short)hi;
        W2l[idx] = (short)f2bf(v - bf2f(hi));
    } else {
        int i = (b - 516) * 256 + t;          // 4 floats per thread
        if (i < N_NODES * 32) {
            f32x4 v = *(const f32x4*)(x + (size_t)i * 4);
            ushort4 h4;
            h4.x = f2bf(v[0]); h4.y = f2bf(v[1]);
            h4.z = f2bf(v[2]); h4.w = f2bf(v[3]);
            *(ushort4*)(nbh + (size_t)i * 4) = h4;
        }
    }
}

// ---------------------------------------------------------------- aggregate (layers 0/1)
// Wave = 4 nodes x 16 lanes; lane owns 8 cols (uint4) end-to-end; edge indices
// (ushort) batch-loaded then shfl-broadcast; unroll-8 for MLP.

__global__ __launch_bounds__(256) void aggregate_kernel(
    const ushort* __restrict__ hb, const int* __restrict__ cursor,
    const ushort* __restrict__ col, uint32_t* __restrict__ aggh)
{
    int node = blockIdx.x * 16 + (threadIdx.x >> 4);
    int cl = threadIdx.x & 15;            // uint4 chunk: cols 8cl..8cl+7
    if (node >= N_NODES) return;

    int beg = node * MAXDEG;
    int deg = min(cursor[node], MAXDEG);

    const ushort* gcol = hb + cl * 8;
    float s0 = 0.f, s1 = 0.f, s2 = 0.f, s3 = 0.f;
    float s4 = 0.f, s5 = 0.f, s6 = 0.f, s7 = 0.f;

#define ACCUM(U) do {                                                        \
        s0 += __builtin_bit_cast(float, (U).x << 16);                        \
        s1 += __builtin_bit_cast(float, (U).x & 0xffff0000u);                \
        s2 += __builtin_bit_cast(float, (U).y << 16);                        \
        s3 += __builtin_bit_cast(float, (U).y & 0xffff0000u);                \
        s4 += __builtin_bit_cast(float, (U).z << 16);                        \
        s5 += __builtin_bit_cast(float, (U).z & 0xffff0000u);                \
        s6 += __builtin_bit_cast(float, (U).w << 16);                        \
        s7 += __builtin_bit_cast(float, (U).w & 0xffff0000u);                \
    } while (0)

    for (int j = 0; j < deg; j += 16) {
        int nb = min(16, deg - j);
        int myidx = (j + cl < deg) ? (int)col[beg + j + cl] : 0;
        int t = 0;
        for (; t + 7 < nb; t += 8) {
            int i0 = __shfl(myidx, t, 16);
            int i1 = __shfl(myidx, t + 1, 16);
            int i2 = __shfl(myidx, t + 2, 16);
            int i3 = __shfl(myidx, t + 3, 16);
            int i4 = __shfl(myidx, t + 4, 16);
            int i5 = __shfl(myidx, t + 5, 16);
            int i6 = __shfl(myidx, t + 6, 16);
            int i7 = __shfl(myidx, t + 7, 16);
            uint4 u0 = *(const uint4*)(gcol + (size_t)i0 * 128);
            uint4 u1 = *(const uint4*)(gcol + (size_t)i1 * 128);
            uint4 u2 = *(const uint4*)(gcol + (size_t)i2 * 128);
            uint4 u3 = *(const uint4*)(gcol + (size_t)i3 * 128);
            uint4 u4 = *(const uint4*)(gcol + (size_t)i4 * 128);
            uint4 u5 = *(const uint4*)(gcol + (size_t)i5 * 128);
            uint4 u6 = *(const uint4*)(gcol + (size_t)i6 * 128);
            uint4 u7 = *(const uint4*)(gcol + (size_t)i7 * 128);
            ACCUM(u0); ACCUM(u1); ACCUM(u2); ACCUM(u3);
            ACCUM(u4); ACCUM(u5); ACCUM(u6); ACCUM(u7);
        }
        for (; t + 3 < nb; t += 4) {
            int i0 = __shfl(myidx, t, 16);
            int i1 = __shfl(myidx, t + 1, 16);
            int i2 = __shfl(myidx, t + 2, 16);
            int i3 = __shfl(myidx, t + 3, 16);
            uint4 u0 = *(const uint4*)(gcol + (size_t)i0 * 128);
            uint4 u1 = *(const uint4*)(gcol + (size_t)i1 * 128);
            uint4 u2 = *(const uint4*)(gcol + (size_t)i2 * 128);
            uint4 u3 = *(const uint4*)(gcol + (size_t)i3 * 128);
            ACCUM(u0); ACCUM(u1); ACCUM(u2); ACCUM(u3);
        }
        for (; t < nb; ++t) {
            int i0 = __shfl(myidx, t, 16);
            uint4 u0 = *(const uint4*)(gcol + (size_t)i0 * 128);
            ACCUM(u0);
        }
    }
#undef ACCUM

    float dinv = 1.0f / (float)max(deg, 1);
    ushort h0 = f2bf(s0 * dinv), h1 = f2bf(s1 * dinv);
    ushort h2 = f2bf(s2 * dinv), h3 = f2bf(s3 * dinv);
    ushort h4 = f2bf(s4 * dinv), h5 = f2bf(s5 * dinv);
    ushort h6 = f2bf(s6 * dinv), h7 = f2bf(s7 * dinv);
    uint4 w;
    w.x = (uint32_t)h0 | ((uint32_t)h1 << 16);
    w.y = (uint32_t)h2 | ((uint32_t)h3 << 16);
    w.z = (uint32_t)h4 | ((uint32_t)h5 << 16);
    w.w = (uint32_t)h6 | ((uint32_t)h7 << 16);
    ((uint4*)aggh)[(size_t)node * 16 + cl] = w;
}

// ---------------------------------------------------------------- aggregate_out (layer 2, transform-first)
// T = [u|v] bf16 per row (128 cols). Gathers v (128B rows), fuses
// out = u + mean(v[src]). Wave = 8 nodes x 8 lanes.

__global__ __launch_bounds__(256) void aggregate_out_kernel(
    const ushort* __restrict__ T, const int* __restrict__ cursor,
    const ushort* __restrict__ col, float* __restrict__ out)
{
    int node = blockIdx.x * 32 + (threadIdx.x >> 3);
    int cl = threadIdx.x & 7;             // uint4 chunk: cols 8cl..8cl+7 of v
    if (node >= N_NODES) return;

    int beg = node * MAXDEG;
    int deg = min(cursor[node], MAXDEG);

    const ushort* gcol = T + 64 + cl * 8;  // v = cols 64..127
    float s0 = 0.f, s1 = 0.f, s2 = 0.f, s3 = 0.f;
    float s4 = 0.f, s5 = 0.f, s6 = 0.f, s7 = 0.f;

#define ACCUM(U) do {                                                        \
        s0 += __builtin_bit_cast(float, (U).x << 16);                        \
        s1 += __builtin_bit_cast(float, (U).x & 0xffff0000u);                \
        s2 += __builtin_bit_cast(float, (U).y << 16);                        \
        s3 += __builtin_bit_cast(float, (U).y & 0xffff0000u);                \
        s4 += __builtin_bit_cast(float, (U).z << 16);                        \
        s5 += __builtin_bit_cast(float, (U).z & 0xffff0000u);                \
        s6 += __builtin_bit_cast(float, (U).w << 16);                        \
        s7 += __builtin_bit_cast(float, (U).w & 0xffff0000u);                \
    } while (0)

    for (int j = 0; j < deg; j += 8) {
        int nb = min(8, deg - j);
        int myidx = (j + cl < deg) ? (int)col[beg + j + cl] : 0;
        int t = 0;
        for (; t + 3 < nb; t += 4) {
            int i0 = __shfl(myidx, t, 8);
            int i1 = __shfl(myidx, t + 1, 8);
            int i2 = __shfl(myidx, t + 2, 8);
            int i3 = __shfl(myidx, t + 3, 8);
            uint4 u0 = *(const uint4*)(gcol + (size_t)i0 * 128);
            uint4 u1 = *(const uint4*)(gcol + (size_t)i1 * 128);
            uint4 u2 = *(const uint4*)(gcol + (size_t)i2 * 128);
            uint4 u3 = *(const uint4*)(gcol + (size_t)i3 * 128);
            ACCUM(u0); ACCUM(u1); ACCUM(u2); ACCUM(u3);
        }
        for (; t < nb; ++t) {
            int i0 = __shfl(myidx, t, 8);
            uint4 u0 = *(const uint4*)(gcol + (size_t)i0 * 128);
            ACCUM(u0);
        }
    }
#undef ACCUM

    float dinv = 1.0f / (float)max(deg, 1);
    uint4 uu = *(const uint4*)(T + (size_t)node * 128 + cl * 8);
    float4 o0, o1;
    o0.x = __builtin_bit_cast(float, uu.x << 16)          + s0 * dinv;
    o0.y = __builtin_bit_cast(float, uu.x & 0xffff0000u)  + s1 * dinv;
    o0.z = __builtin_bit_cast(float, uu.y << 16)          + s2 * dinv;
    o0.w = __builtin_bit_cast(float, uu.y & 0xffff0000u)  + s3 * dinv;
    o1.x = __builtin_bit_cast(float, uu.z << 16)          + s4 * dinv;
    o1.y = __builtin_bit_cast(float, uu.z & 0xffff0000u)  + s5 * dinv;
    o1.z = __builtin_bit_cast(float, uu.w << 16)          + s6 * dinv;
    o1.w = __builtin_bit_cast(float, uu.w & 0xffff0000u)  + s7 * dinv;
    *(float4*)(out + (size_t)node * 64 + cl * 8)     = o0;
    *(float4*)(out + (size_t)node * 64 + cl * 8 + 4) = o1;
}

// ---------------------------------------------------------------- combine GEMM v13 (layers 0/1, plain bf16 both sides)

template <int NOUT, int CB, bool RELU>
__global__ __launch_bounds__(512) void combine_mfma13(
    const ushort* __restrict__ nbh, const ushort* __restrict__ aggh,
    const short* __restrict__ Wth,
    const float* __restrict__ bias, ushort* __restrict__ oh)
{
    __shared__ __attribute__((aligned(16))) short Bh[64 * 33 * 8];

    const int id  = blockIdx.x;          // grid = 8 * 25 * CB
    const int xcd = id & 7;
    const int k   = id >> 3;
    const int rb  = k / CB;
    const int cnt_x = (xcd < 4) ? 25 : 24;
    if (rb >= cnt_x) return;
    const int base  = (xcd < 4) ? xcd * 25 : 100 + (xcd - 4) * 24;
    const int row0    = (base + rb) * 256;
    const int colbase = (k % CB) * 64;

    const int tid  = threadIdx.x;
    const int lane = tid & 63;
    const int wave = tid >> 6;
    const int rr = lane & 15;
    const int kq = lane >> 4;

    // stage B once: 64 cols x 32 chunks (2048 chunks / 512 thr = 4 each)
    {
        int col = tid >> 3;
        int kc0 = (tid & 7) * 4;
        const short* gh = Wth + (size_t)(colbase + col) * 256 + kc0 * 8;
        #pragma unroll
        for (int j = 0; j < 4; ++j)
            ((bf16x8*)Bh)[col * 33 + kc0 + j] = *(const bf16x8*)(gh + j * 8);
    }

    const size_t arow0 = (size_t)(row0 + wave * 32 + rr) * 128;
    const size_t arow1 = arow0 + (size_t)16 * 128;

    f32x4 acc[2][4];
    #pragma unroll
    for (int i = 0; i < 2; ++i)
        #pragma unroll
        for (int j = 0; j < 4; ++j)
            acc[i][j] = (f32x4){0.f, 0.f, 0.f, 0.f};

    __syncthreads();

#define COMPUTE(KS) do {                                                    \
        const ushort* bs_ = ((KS) < 4) ? nbh : aggh;                        \
        const int kf_ = ((KS) & 3) * 32 + kq * 8;                           \
        bf16x8 aA = *(const bf16x8*)(bs_ + arow0 + kf_);                    \
        bf16x8 aB = *(const bf16x8*)(bs_ + arow1 + kf_);                    \
        _Pragma("unroll")                                                   \
        for (int nj = 0; nj < 4; ++nj) {                                    \
            int colL = nj * 16 + rr;                                        \
            bf16x8 bh = ((const bf16x8*)Bh)[colL * 33 + (KS) * 4 + kq];     \
            acc[0][nj] = __builtin_amdgcn_mfma_f32_16x16x32_bf16(aA, bh, acc[0][nj], 0, 0, 0); \
            acc[1][nj] = __builtin_amdgcn_mfma_f32_16x16x32_bf16(aB, bh, acc[1][nj], 0, 0, 0); \
        }                                                                   \
    } while (0)

    COMPUTE(0); COMPUTE(1); COMPUTE(2); COMPUTE(3);
    COMPUTE(4); COMPUTE(5); COMPUTE(6); COMPUTE(7);
#undef COMPUTE

    const int rg = lane >> 4;
    #pragma unroll
    for (int nj = 0; nj < 4; ++nj) {
        int colg = colbase + nj * 16 + rr;
        float bv = bias[colg];
        #pragma unroll
        for (int mi = 0; mi < 2; ++mi) {
            #pragma unroll
            for (int r = 0; r < 4; ++r) {
                int row = row0 + wave * 32 + mi * 16 + rg * 4 + r;
                if (row < N_NODES) {
                    float v = acc[mi][nj][r] + bv;
                    if (RELU) v = fmaxf(v, 0.f);
                    oh[(size_t)row * NOUT + colg] = f2bf(v);
                }
            }
        }
    }
}

// ---------------------------------------------------------------- combine GEMM v12 (layer 2, transform-first, B hi/lo)
// T[n] = hB[n] @ [Ws2|Wn2] (+ [b2|0]), K=128, NOUT=128, bf16 out.

__global__ __launch_bounds__(512, 4) void combine_mfma12(
    const ushort* __restrict__ hb,
    const short* __restrict__ Wth, const short* __restrict__ Wtl,
    const float* __restrict__ b2, ushort* __restrict__ T)
{
    __shared__ __attribute__((aligned(16))) short Bh[128 * 17 * 8];
    __shared__ __attribute__((aligned(16))) short Bl[128 * 17 * 8];

    const int id  = blockIdx.x;          // grid = 200
    const int xcd = id & 7;
    const int k   = id >> 3;
    const int cnt_x = (xcd < 4) ? 25 : 24;
    if (k >= cnt_x) return;
    const int base = (xcd < 4) ? xcd * 25 : 100 + (xcd - 4) * 24;
    const int row0 = (base + k) * 256;

    const int tid  = threadIdx.x;
    const int lane = tid & 63;
    const int wave = tid >> 6;
    const int rr = lane & 15;
    const int kq = lane >> 4;

    {
        int col = tid >> 2;              // 0..127
        int kc0 = (tid & 3) * 4;
        const short* gh = Wth + (size_t)col * 128 + kc0 * 8;
        const short* gl = Wtl + (size_t)col * 128 + kc0 * 8;
        #pragma unroll
        for (int j = 0; j < 4; ++j) {
            ((bf16x8*)Bh)[col * 17 + kc0 + j] = *(const bf16x8*)(gh + j * 8);
            ((bf16x8*)Bl)[col * 17 + kc0 + j] = *(const bf16x8*)(gl + j * 8);
        }
    }

    const size_t arow0 = (size_t)(row0 + wave * 32 + rr) * 128;
    const size_t arow1 = arow0 + (size_t)16 * 128;

    f32x4 acc[2][8];
    #pragma unroll
    for (int i = 0; i < 2; ++i)
        #pragma unroll
        for (int j = 0; j < 8; ++j)
            acc[i][j] = (f32x4){0.f, 0.f, 0.f, 0.f};

    __syncthreads();

#define COMPUTE(KS) do {                                                    \
        const int kf_ = (KS) * 32 + kq * 8;                                 \
        bf16x8 aA = *(const bf16x8*)(hb + arow0 + kf_);                     \
        bf16x8 aB = *(const bf16x8*)(hb + arow1 + kf_);                     \
        _Pragma("unroll")                                                   \
        for (int nj = 0; nj < 8; ++nj) {                                    \
            int colL = nj * 16 + rr;                                        \
            bf16x8 bh = ((const bf16x8*)Bh)[colL * 17 + (KS) * 4 + kq];     \
            bf16x8 bl = ((const bf16x8*)Bl)[colL * 17 + (KS) * 4 + kq];     \
            acc[0][nj] = __builtin_amdgcn_mfma_f32_16x16x32_bf16(aA, bh, acc[0][nj], 0, 0, 0); \
            acc[0][nj] = __builtin_amdgcn_mfma_f32_16x16x32_bf16(aA, bl, acc[0][nj], 0, 0, 0); \
            acc[1][nj] = __builtin_amdgcn_mfma_f32_16x16x32_bf16(aB, bh, acc[1][nj], 0, 0, 0); \
            acc[1][nj] = __builtin_amdgcn_mfma_f32_16x16x32_bf16(aB, bl, acc[1][nj], 0, 0, 0); \
        }                                                                   \
    } while (0)

    COMPUTE(0); COMPUTE(1); COMPUTE(2); COMPUTE(3);
#undef COMPUTE

    const int rg = lane >> 4;
    #pragma unroll
    for (int nj = 0; nj < 8; ++nj) {
        int colg = nj * 16 + rr;
        float bv = (colg < 64) ? b2[colg] : 0.f;
        #pragma unroll
        for (int mi = 0; mi < 2; ++mi) {
            #pragma unroll
            for (int r = 0; r < 4; ++r) {
                int row = row0 + wave * 32 + mi * 16 + rg * 4 + r;
                T[(size_t)row * 128 + colg] = f2bf(acc[mi][nj][r] + bv);
            }
        }
    }
}

// ---------------------------------------------------------------- launch

extern "C" void kernel_launch(void* const* d_in, const int* in_sizes, int n_in,
                              void* d_out, int out_size, void* d_ws, size_t ws_size,
                              hipStream_t stream) {
    const float* x   = (const float*)d_in[0];
    const int*   src = (const int*)d_in[1];
    const int*   dst = (const int*)d_in[2];
    const float* Ws0 = (const float*)d_in[3];
    const float* Wn0 = (const float*)d_in[4];
    const float* b0  = (const float*)d_in[5];
    const float* Ws1 = (const float*)d_in[6];
    const float* Wn1 = (const float*)d_in[7];
    const float* b1  = (const float*)d_in[8];
    const float* Ws2 = (const float*)d_in[9];
    const float* Wn2 = (const float*)d_in[10];
    const float* b2  = (const float*)d_in[11];
    float* out = (float*)d_out;

    char* p = (char*)d_ws;
    auto alloc = [&](size_t bytes) {
        char* r = p;
        p += (bytes + 255) & ~(size_t)255;
        return r;
    };
    int*      cursor   = (int*)alloc((size_t)N_NODES * 4);
    ushort*   col      = (ushort*)alloc((size_t)N_NODES * MAXDEG * 2);
    uint32_t* aggh     = (uint32_t*)alloc((size_t)PADROWS * 64 * 4);
    ushort*   nbh0     = (ushort*)alloc((size_t)PADROWS * 128 * 2);
    ushort*   nbh1     = (ushort*)alloc((size_t)PADROWS * 128 * 2);
    ushort*   Tbuf     = (ushort*)alloc((size_t)PADROWS * 128 * 2);
    short*    Wt0_hi   = (short*)alloc((size_t)128 * 256 * 2);
    short*    Wt1_hi   = (short*)alloc((size_t)128 * 256 * 2);
    short*    Wt2_hi   = (short*)alloc((size_t)128 * 128 * 2);
    short*    Wt2_lo   = (short*)alloc((size_t)128 * 128 * 2);

    // prep: zero(cursor) + W0/W1 hi + W2 hi/lo + x cast — one launch
    prep_kernel<<<516 + (N_NODES * 32 + 255) / 256, 256, 0, stream>>>(
        Ws0, Wn0, Ws1, Wn1, Ws2, Wn2, x, cursor,
        Wt0_hi, Wt1_hi, Wt2_hi, Wt2_lo, nbh0);

    // adjacency build (XCD-partitioned; padded ushort lists)
    fill_kernel<<<8 * FILLG, 256, 0, stream>>>(src, dst, cursor, col);

    const int AGB = (N_NODES + 15) / 16;      // 3125

    // layer 0
    aggregate_kernel<<<AGB, 256, 0, stream>>>(nbh0, cursor, col, aggh);
    combine_mfma13<128, 2, true><<<8 * 25 * 2, 512, 0, stream>>>(
        nbh0, (const ushort*)aggh, Wt0_hi, b0, nbh1);
    // layer 1
    aggregate_kernel<<<AGB, 256, 0, stream>>>(nbh1, cursor, col, aggh);
    combine_mfma13<128, 2, true><<<8 * 25 * 2, 512, 0, stream>>>(
        nbh1, (const ushort*)aggh, Wt1_hi, b1, nbh0);
    // layer 2: transform-first — T = hB@[Ws2|Wn2]+[b2|0], then gather v + add u
    combine_mfma12<<<8 * 25, 512, 0, stream>>>(nbh0, Wt2_hi, Wt2_lo, b2, Tbuf);
    aggregate_out_kernel<<<(N_NODES + 31) / 32, 256, 0, stream>>>(Tbuf, cursor, col, out);
}